// Round 12
// baseline (682.142 us; speedup 1.0000x reference)
//
#include <hip/hip_runtime.h>
#include <cstdint>
#include <cstddef>

typedef __attribute__((ext_vector_type(8))) __bf16 bf16x8;
typedef __attribute__((ext_vector_type(16))) float floatx16;

struct SrcPtrs { const float* p[9]; };

// ---------------- weight workspace layout (bf16 elems) ----------------
// Frag-major per layer: frag f = t*S + s (t = 32-feature tile, s = 16-k step).
// Each frag = 1024 B = 64 lanes x 16 B; lane l = q2*32 + l31 holds
// row (32t + l31), k = 16s + 8*q2 + {0..7} — the 32x32x16 bf16 A layout.
// r7: the k index additionally carries the involution phi = swap bits 2,3 of
// (k & 15). With phi baked into the stored weights AND the trig feature
// mapping, the packed C-output registers of layer L are BIT-IDENTICAL to the
// B-fragments of layer L+1 -> no cross-lane half-swap, no B-build.
// m  mat    K    Nout  S   NT  off(shorts)  remap
// 0  Wd1_0  60   128   4   4   0
// 1  Wd1_1  128  128   8   4   8192
// 2  Wd1_2  128  128   8   4   24576
// 3  Wd2_0  188  128   12  4   40960    k<60 -> 128+k, k>=60 -> k-60
// 4  Wd2_1  128  128   8   4   65536
// 5  Wd2_2  128  128   8   4   81920
// 6  Wd2_3  128  129   8   5   98304    col0 -> row128 (blend), col j+1 -> row j
// 7  Wc_0   152  128   10  4   118784   k<24 -> 128+k, k>=24 -> k-24
// 8  Wc_1   128  3     8   1   139264   rows 3..31 zero
// total 143360 shorts = 286720 B (L2-resident per XCD after first touch)

__global__ void prep_zero(unsigned short* __restrict__ ws) {
  uint4* p = (uint4*)ws;
  const int n = 143360 / 8;
  for (int i = blockIdx.x * blockDim.x + threadIdx.x; i < n; i += gridDim.x * blockDim.x)
    p[i] = make_uint4(0u, 0u, 0u, 0u);
}

__global__ void prep_fill(SrcPtrs sp, unsigned short* __restrict__ ws) {
  const int m  = blockIdx.x >> 4;
  const int sl = blockIdx.x & 15;
  const int K[9]  = {60, 128, 128, 188, 128, 128, 128, 152, 128};
  const int N[9]  = {128, 128, 128, 128, 128, 128, 129, 128, 3};
  const int SS[9] = {4, 8, 8, 12, 8, 8, 8, 10, 8};
  const unsigned OFF[9] = {0u, 8192u, 24576u, 40960u, 65536u, 81920u, 98304u, 118784u, 139264u};
  const int Km = K[m], Nm = N[m], Sm = SS[m];
  const float* __restrict__ src = sp.p[m];
  unsigned short* __restrict__ dst = ws + OFF[m];
  const int tot = Km * Nm;
  for (int i = sl * 256 + (int)threadIdx.x; i < tot; i += 16 * 256) {
    int k = i / Nm;
    int n = i - k * Nm;
    int kk = k, row = n;
    if (m == 3) kk = (k < 60) ? 128 + k : k - 60;
    if (m == 7) kk = (k < 24) ? 128 + k : k - 24;
    if (m == 6) row = (n == 0) ? 128 : n - 1;
    // phi: swap bits 2,3 of the k low nibble (involution). Makes packed
    // C-outputs feed MFMA-B directly (see header comment).
    kk = (kk & ~12) | (((kk & 4) << 1) | ((kk & 8) >> 1));
    const int t = row >> 5, l31 = row & 31;
    const int s = kk >> 4, q2 = (kk >> 3) & 1, j = kk & 7;
    dst[(t * Sm + s) * 512 + (q2 * 32 + l31) * 8 + j] =
        __builtin_bit_cast(unsigned short, (__bf16)src[i]);
  }
}

// ---------------- main fused kernel ----------------

__device__ __forceinline__ unsigned pk2(float a, float b) {
  unsigned short ua = __builtin_bit_cast(unsigned short, (__bf16)a);
  unsigned short ub = __builtin_bit_cast(unsigned short, (__bf16)b);
  return (unsigned)ua | ((unsigned)ub << 16);
}

// sin/cos of v * pi * 2^f == sin/cos(2*pi*rev), rev = v * 2^(f-1) (HW revolutions)
// phi-adjusted feature mapping: lane q2, element j supplies feature
// f = 16*sl + j + 4*q2 + (j>=4 ? 4 : 0)   (= phi(16*sl + 8*q2 + j)).
// KIND 0: positional enc: d=f/20, scale from f%20, valid f<60
// KIND 1: view enc: d=3+f/8, scale from f%8, valid f<24
template <int KIND>
__device__ __forceinline__ bf16x8 trig_frag(const float (&x)[6], int q2, int sl) {
  bf16x8 r;
#pragma unroll
  for (int j = 0; j < 8; ++j) {
    const int kA = 16 * sl + j + (j >= 4 ? 4 : 0);  // q2 == 0 feature
    const int kB = kA + 4;                          // q2 == 1 feature
    int dA, dB; float scA, scB; bool vA, vB;
    if (KIND == 0) {
      vA = kA < 60; vB = kB < 60;
      dA = kA / 20; dB = kB / 20;
      scA = (float)(1 << ((kA % 20) >> 1)) * 0.5f;
      scB = (float)(1 << ((kB % 20) >> 1)) * 0.5f;
    } else {
      vA = kA < 24; vB = kB < 24;
      dA = 3 + (kA >> 3); dB = 3 + (kB >> 3);
      scA = (float)(1 << ((kA & 7) >> 1)) * 0.5f;
      scB = (float)(1 << ((kB & 7) >> 1)) * 0.5f;
    }
    float v  = q2 ? x[dB] : x[dA];
    float sc = q2 ? scB : scA;
    bool ok  = q2 ? vB : vA;
    float rev = v * sc;
    float t = (j & 1) ? __builtin_amdgcn_cosf(rev) : __builtin_amdgcn_sinf(rev);
    r[j] = (__bf16)(ok ? t : 0.0f);
  }
  return r;
}

// per-tile epilogue. t is a post-unroll constant at every call site.
template <bool RELU, int OUTM>
__device__ __forceinline__ void store_tile(int t, const floatx16& am0, const floatx16& am1,
                                           uint4 (&pout)[2][8], float* __restrict__ out,
                                           int q2, int pt0, int pt1) {
  if (OUTM == 2) {
    if (q2 == 0) {  // rgb = rows 0..2 -> regs 0..2 at q2==0
      float* o0 = out + (size_t)pt0 * 5;
      o0[0] = am0[0]; o0[1] = am0[1]; o0[2] = am0[2];
      float* o1 = out + (size_t)pt1 * 5;
      o1[0] = am1[0]; o1[1] = am1[1]; o1[2] = am1[2];
    }
  } else {
    if (OUTM == 0 || t < 4) {
#pragma unroll
      for (int gg = 0; gg < 4; ++gg) {
        float b0 = am0[4 * gg], b1 = am0[4 * gg + 1];
        float b2 = am0[4 * gg + 2], b3 = am0[4 * gg + 3];
        float c0 = am1[4 * gg], c1 = am1[4 * gg + 1];
        float c2 = am1[4 * gg + 2], c3 = am1[4 * gg + 3];
        if (RELU) {
          b0 = fmaxf(b0, 0.f); b1 = fmaxf(b1, 0.f);
          b2 = fmaxf(b2, 0.f); b3 = fmaxf(b3, 0.f);
          c0 = fmaxf(c0, 0.f); c1 = fmaxf(c1, 0.f);
          c2 = fmaxf(c2, 0.f); c3 = fmaxf(c3, 0.f);
        }
        if ((gg & 1) == 0) {
          pout[0][2 * t + (gg >> 1)].x = pk2(b0, b1);
          pout[0][2 * t + (gg >> 1)].y = pk2(b2, b3);
          pout[1][2 * t + (gg >> 1)].x = pk2(c0, c1);
          pout[1][2 * t + (gg >> 1)].y = pk2(c2, c3);
        } else {
          pout[0][2 * t + (gg >> 1)].z = pk2(b0, b1);
          pout[0][2 * t + (gg >> 1)].w = pk2(b2, b3);
          pout[1][2 * t + (gg >> 1)].z = pk2(c0, c1);
          pout[1][2 * t + (gg >> 1)].w = pk2(c2, c3);
        }
      }
    }
    if (OUTM == 1 && q2 == 0) {
      if (t == 0) {  // density = feature[:,0] = row 0 (f32, pre-rounding)
        out[(size_t)pt0 * 5 + 3] = am0[0];
        out[(size_t)pt1 * 5 + 3] = am1[0];
      }
      if (t == 4) {  // blending = sigmoid(row 128)
        out[(size_t)pt0 * 5 + 4] = 1.0f / (1.0f + __expf(-am0[0]));
        out[(size_t)pt1 * 5 + 4] = 1.0f / (1.0f + __expf(-am1[0]));
      }
    }
  }
}

// 32x32x16 bf16 MFMA, A = weights (m=feature), B = activations (n=point).
// Activations ping-pong between register banks pin/pout (uint4[2][8], feature
// order matching phi'd MFMA-B exactly -> B = bit_cast(pin[m][s]), zero build).
// r12: REGISTER DIET -> 3 WAVES/SIMD. r11 closed the accounting: waves are
// lifetime-bound (issue-ready ~28% each); VALUBusy 54% = 1-(1-.28)^2 with 2
// independent waves/SIMD; MfmaUtil 50% is demand, not a pipe limit. The
// 2-wave cap is the unified register total: arch 124 + AGPR 48 (a0,a1,ZACC)
// = 172 > 170 = 512/3. Diet: drop zacc (explicit per-tile acc init — VALU is
// free, we're latency-bound), DEPTH 8->6, launch_bounds(256,3) pins the
// allocator <=170 (natural ~156, so no spill — unlike r2/r4 at natural ~220).
// Barrier-free all-L2 structure (r11): no LDS -> no LDS occupancy cap.
// S: k-steps. SL: k-steps from pin (rest from tail). NT: 32-feature tiles.
// OUTM: 0=pack pout, 1=d2_3 (pack t<4 + density/blend), 2=c_1 (rgb only).
template <int S, int SL, int NT, bool RELU, int OUTM>
__device__ __forceinline__ void run_layer(const unsigned short* __restrict__ wsrc,
                                          const uint4 (&pin)[2][8],
                                          uint4 (&pout)[2][8],
                                          const bf16x8 (&tail)[2][4],
                                          float* __restrict__ out, int base, int tid) {
  const int lane = tid & 63;
  const int w = tid >> 6;
  const int q2 = lane >> 5;
  const int l31 = lane & 31;
  const int pt0 = base + w * 64 + l31;
  const int pt1 = pt0 + 32;

  const uint4* __restrict__ wp = (const uint4*)wsrc;

  constexpr int TOT = NT * S;
  constexpr int DEPTH = 6;  // 24 VGPR window ~= 384 cyc of L2-latency cover
  bf16x8 win[DEPTH];

  // prologue: fill the window
#pragma unroll
  for (int p = 0; p < DEPTH && p < TOT; ++p)
    win[p] = __builtin_bit_cast(bf16x8, wp[p * 64 + lane]);

  floatx16 a0, a1;
#pragma unroll
  for (int p = 0; p < TOT; ++p) {
    const int t = p / S, s = p % S;
    if (s == 0) {
#pragma unroll
      for (int i = 0; i < 16; ++i) { a0[i] = 0.0f; a1[i] = 0.0f; }
    }
    bf16x8 A = win[p % DEPTH];                       // waits only this slot
    if (p + DEPTH < TOT)
      win[p % DEPTH] = __builtin_bit_cast(bf16x8, wp[(p + DEPTH) * 64 + lane]);
    bf16x8 B0 = (s < SL) ? __builtin_bit_cast(bf16x8, pin[0][(s < SL) ? s : 0])
                         : tail[0][s - SL];
    bf16x8 B1 = (s < SL) ? __builtin_bit_cast(bf16x8, pin[1][(s < SL) ? s : 0])
                         : tail[1][s - SL];
    a0 = __builtin_amdgcn_mfma_f32_32x32x16_bf16(A, B0, a0, 0, 0, 0);
    a1 = __builtin_amdgcn_mfma_f32_32x32x16_bf16(A, B1, a1, 0, 0, 0);
    if (s == S - 1)
      store_tile<RELU, OUTM>(t, a0, a1, pout, out, q2, pt0, pt1);
  }
}

// launch_bounds(256,3): 3 waves/EU target -> total-reg cap 170. Natural live
// set after the diet is ~156 (P banks + window 24 + acc 32 + pkt/x/misc with
// compiler overlap; r11 measured 124 arch + 48 acc with zacc) -> no spill
// expected. Spill tripwire: WRITE_SIZE >> 21 MB. No LDS -> no LDS cap.
__global__ __launch_bounds__(256, 3) void nerf_main(const float* __restrict__ x,
                                                    const unsigned short* __restrict__ ws,
                                                    float* __restrict__ out) {
  const int tid = (int)threadIdx.x;
  const int base = (int)blockIdx.x * 256;
  const int lane = tid & 63;
  const int w = tid >> 6;
  const int q2 = lane >> 5;
  const int l31 = lane & 31;
  const int pt0 = base + w * 64 + l31;

  // per-lane x in registers (pt fixed per lane for whole kernel)
  float x0[6], x1[6];
  {
    const float* a = x + (size_t)pt0 * 6;
    const float* b = x + (size_t)(pt0 + 32) * 6;
#pragma unroll
    for (int c = 0; c < 3; ++c) {
      float2 u = *(const float2*)(a + 2 * c);
      float2 v = *(const float2*)(b + 2 * c);
      x0[2 * c] = u.x; x0[2 * c + 1] = u.y;
      x1[2 * c] = v.x; x1[2 * c + 1] = v.y;
    }
  }

  // positional trig frags computed ONCE (used by d1_0 and d2_0)
  bf16x8 pkt[2][4];
#pragma unroll
  for (int sl = 0; sl < 4; ++sl) {
    pkt[0][sl] = trig_frag<0>(x0, q2, sl);
    pkt[1][sl] = trig_frag<0>(x1, q2, sl);
  }

  // activation ping-pong register banks
  uint4 P0[2][8], P1[2][8];

  //          S   SL NT relu  out     wsrc
  run_layer< 4, 0, 4, true , 0>(ws + 0u,      P0, P0, pkt, out, base, tid); // d1_0 (in unused)
  run_layer< 8, 8, 4, true , 0>(ws + 8192u,   P0, P1, pkt, out, base, tid); // d1_1
  run_layer< 8, 8, 4, false, 0>(ws + 24576u,  P1, P0, pkt, out, base, tid); // d1_2 -> part1
  run_layer<12, 8, 4, true , 0>(ws + 40960u,  P0, P1, pkt, out, base, tid); // d2_0 [part1|enc_pos]
  run_layer< 8, 8, 4, true , 0>(ws + 65536u,  P1, P0, pkt, out, base, tid); // d2_1
  run_layer< 8, 8, 4, true , 0>(ws + 81920u,  P0, P1, pkt, out, base, tid); // d2_2
  run_layer< 8, 8, 5, false, 1>(ws + 98304u,  P1, P0, pkt, out, base, tid); // d2_3

  // view trig frags (pkt regs dead after d2_0 -> reuse pressure window)
  // only [*][0..1] are ever read (c_0: S-SL = 2 tail steps)
  bf16x8 vw[2][4];
#pragma unroll
  for (int sl = 0; sl < 2; ++sl) {
    vw[0][sl] = trig_frag<1>(x0, q2, sl);
    vw[1][sl] = trig_frag<1>(x1, q2, sl);
  }
  vw[0][2] = vw[0][0]; vw[0][3] = vw[0][0];
  vw[1][2] = vw[1][0]; vw[1][3] = vw[1][0];

  run_layer<10, 8, 4, true , 0>(ws + 118784u, P0, P1, vw,  out, base, tid); // c_0 [feature|enc_view]
  run_layer< 8, 8, 1, false, 2>(ws + 139264u, P1, P0, pkt, out, base, tid); // c_1 -> rgb
}

extern "C" void kernel_launch(void* const* d_in, const int* in_sizes, int n_in,
                              void* d_out, int out_size, void* d_ws, size_t ws_size,
                              hipStream_t stream) {
  (void)n_in; (void)out_size; (void)ws_size;
  const float* x = (const float*)d_in[0];
  SrcPtrs sp;
  for (int i = 0; i < 9; ++i) sp.p[i] = (const float*)d_in[1 + i];
  unsigned short* ws = (unsigned short*)d_ws;
  float* out = (float*)d_out;
  const int N = in_sizes[0] / 6;

  prep_zero<<<70, 256, 0, stream>>>(ws);
  prep_fill<<<144, 256, 0, stream>>>(sp, ws);
  nerf_main<<<N / 256, 256, 0, stream>>>(x, ws, out);
}

// Round 13
// 338.844 us; speedup vs baseline: 2.0131x; 2.0131x over previous
//
#include <hip/hip_runtime.h>
#include <cstdint>
#include <cstddef>

typedef __attribute__((ext_vector_type(8))) __bf16 bf16x8;
typedef __attribute__((ext_vector_type(16))) float floatx16;

struct SrcPtrs { const float* p[9]; };

// ---------------- weight workspace layout (bf16 elems) ----------------
// Frag-major per layer: frag f = t*S + s (t = 32-feature tile, s = 16-k step).
// Each frag = 1024 B = 64 lanes x 16 B; lane l = q2*32 + l31 holds
// row (32t + l31), k = 16s + 8*q2 + {0..7} — the 32x32x16 bf16 A layout.
// r7: the k index additionally carries the involution phi = swap bits 2,3 of
// (k & 15). With phi baked into the stored weights AND the trig feature
// mapping, the packed C-output registers of layer L are BIT-IDENTICAL to the
// B-fragments of layer L+1 -> no cross-lane half-swap, no B-build.
// m  mat    K    Nout  S   NT  off(shorts)  remap
// 0  Wd1_0  60   128   4   4   0
// 1  Wd1_1  128  128   8   4   8192
// 2  Wd1_2  128  128   8   4   24576
// 3  Wd2_0  188  128   12  4   40960    k<60 -> 128+k, k>=60 -> k-60
// 4  Wd2_1  128  128   8   4   65536
// 5  Wd2_2  128  128   8   4   81920
// 6  Wd2_3  128  129   8   5   98304    col0 -> row128 (blend), col j+1 -> row j
// 7  Wc_0   152  128   10  4   118784   k<24 -> 128+k, k>=24 -> k-24
// 8  Wc_1   128  3     8   1   139264   rows 3..31 zero
// total 143360 shorts = 286720 B (L2-resident per XCD after first touch)

__global__ void prep_zero(unsigned short* __restrict__ ws) {
  uint4* p = (uint4*)ws;
  const int n = 143360 / 8;
  for (int i = blockIdx.x * blockDim.x + threadIdx.x; i < n; i += gridDim.x * blockDim.x)
    p[i] = make_uint4(0u, 0u, 0u, 0u);
}

__global__ void prep_fill(SrcPtrs sp, unsigned short* __restrict__ ws) {
  const int m  = blockIdx.x >> 4;
  const int sl = blockIdx.x & 15;
  const int K[9]  = {60, 128, 128, 188, 128, 128, 128, 152, 128};
  const int N[9]  = {128, 128, 128, 128, 128, 128, 129, 128, 3};
  const int SS[9] = {4, 8, 8, 12, 8, 8, 8, 10, 8};
  const unsigned OFF[9] = {0u, 8192u, 24576u, 40960u, 65536u, 81920u, 98304u, 118784u, 139264u};
  const int Km = K[m], Nm = N[m], Sm = SS[m];
  const float* __restrict__ src = sp.p[m];
  unsigned short* __restrict__ dst = ws + OFF[m];
  const int tot = Km * Nm;
  for (int i = sl * 256 + (int)threadIdx.x; i < tot; i += 16 * 256) {
    int k = i / Nm;
    int n = i - k * Nm;
    int kk = k, row = n;
    if (m == 3) kk = (k < 60) ? 128 + k : k - 60;
    if (m == 7) kk = (k < 24) ? 128 + k : k - 24;
    if (m == 6) row = (n == 0) ? 128 : n - 1;
    // phi: swap bits 2,3 of the k low nibble (involution). Makes packed
    // C-outputs feed MFMA-B directly (see header comment).
    kk = (kk & ~12) | (((kk & 4) << 1) | ((kk & 8) >> 1));
    const int t = row >> 5, l31 = row & 31;
    const int s = kk >> 4, q2 = (kk >> 3) & 1, j = kk & 7;
    dst[(t * Sm + s) * 512 + (q2 * 32 + l31) * 8 + j] =
        __builtin_bit_cast(unsigned short, (__bf16)src[i]);
  }
}

// ---------------- main fused kernel ----------------

__device__ __forceinline__ unsigned pk2(float a, float b) {
  unsigned short ua = __builtin_bit_cast(unsigned short, (__bf16)a);
  unsigned short ub = __builtin_bit_cast(unsigned short, (__bf16)b);
  return (unsigned)ua | ((unsigned)ub << 16);
}

// sin/cos of v * pi * 2^f == sin/cos(2*pi*rev), rev = v * 2^(f-1) (HW revolutions)
// phi-adjusted feature mapping: lane q2, element j supplies feature
// f = 16*sl + j + 4*q2 + (j>=4 ? 4 : 0)   (= phi(16*sl + 8*q2 + j)).
// KIND 0: positional enc: d=f/20, scale from f%20, valid f<60
// KIND 1: view enc: d=3+f/8, scale from f%8, valid f<24
template <int KIND>
__device__ __forceinline__ bf16x8 trig_frag(const float (&x)[6], int q2, int sl) {
  bf16x8 r;
#pragma unroll
  for (int j = 0; j < 8; ++j) {
    const int kA = 16 * sl + j + (j >= 4 ? 4 : 0);  // q2 == 0 feature
    const int kB = kA + 4;                          // q2 == 1 feature
    int dA, dB; float scA, scB; bool vA, vB;
    if (KIND == 0) {
      vA = kA < 60; vB = kB < 60;
      dA = kA / 20; dB = kB / 20;
      scA = (float)(1 << ((kA % 20) >> 1)) * 0.5f;
      scB = (float)(1 << ((kB % 20) >> 1)) * 0.5f;
    } else {
      vA = kA < 24; vB = kB < 24;
      dA = 3 + (kA >> 3); dB = 3 + (kB >> 3);
      scA = (float)(1 << ((kA & 7) >> 1)) * 0.5f;
      scB = (float)(1 << ((kB & 7) >> 1)) * 0.5f;
    }
    float v  = q2 ? x[dB] : x[dA];
    float sc = q2 ? scB : scA;
    bool ok  = q2 ? vB : vA;
    float rev = v * sc;
    float t = (j & 1) ? __builtin_amdgcn_cosf(rev) : __builtin_amdgcn_sinf(rev);
    r[j] = (__bf16)(ok ? t : 0.0f);
  }
  return r;
}

// per-tile epilogue. t is a post-unroll constant at every call site.
template <bool RELU, int OUTM>
__device__ __forceinline__ void store_tile(int t, const floatx16& am0, const floatx16& am1,
                                           uint4 (&pout)[2][8], float* __restrict__ out,
                                           int q2, int pt0, int pt1) {
  if (OUTM == 2) {
    if (q2 == 0) {  // rgb = rows 0..2 -> regs 0..2 at q2==0
      float* o0 = out + (size_t)pt0 * 5;
      o0[0] = am0[0]; o0[1] = am0[1]; o0[2] = am0[2];
      float* o1 = out + (size_t)pt1 * 5;
      o1[0] = am1[0]; o1[1] = am1[1]; o1[2] = am1[2];
    }
  } else {
    if (OUTM == 0 || t < 4) {
#pragma unroll
      for (int gg = 0; gg < 4; ++gg) {
        float b0 = am0[4 * gg], b1 = am0[4 * gg + 1];
        float b2 = am0[4 * gg + 2], b3 = am0[4 * gg + 3];
        float c0 = am1[4 * gg], c1 = am1[4 * gg + 1];
        float c2 = am1[4 * gg + 2], c3 = am1[4 * gg + 3];
        if (RELU) {
          b0 = fmaxf(b0, 0.f); b1 = fmaxf(b1, 0.f);
          b2 = fmaxf(b2, 0.f); b3 = fmaxf(b3, 0.f);
          c0 = fmaxf(c0, 0.f); c1 = fmaxf(c1, 0.f);
          c2 = fmaxf(c2, 0.f); c3 = fmaxf(c3, 0.f);
        }
        if ((gg & 1) == 0) {
          pout[0][2 * t + (gg >> 1)].x = pk2(b0, b1);
          pout[0][2 * t + (gg >> 1)].y = pk2(b2, b3);
          pout[1][2 * t + (gg >> 1)].x = pk2(c0, c1);
          pout[1][2 * t + (gg >> 1)].y = pk2(c2, c3);
        } else {
          pout[0][2 * t + (gg >> 1)].z = pk2(b0, b1);
          pout[0][2 * t + (gg >> 1)].w = pk2(b2, b3);
          pout[1][2 * t + (gg >> 1)].z = pk2(c0, c1);
          pout[1][2 * t + (gg >> 1)].w = pk2(c2, c3);
        }
      }
    }
    if (OUTM == 1 && q2 == 0) {
      if (t == 0) {  // density = feature[:,0] = row 0 (f32, pre-rounding)
        out[(size_t)pt0 * 5 + 3] = am0[0];
        out[(size_t)pt1 * 5 + 3] = am1[0];
      }
      if (t == 4) {  // blending = sigmoid(row 128)
        out[(size_t)pt0 * 5 + 4] = 1.0f / (1.0f + __expf(-am0[0]));
        out[(size_t)pt1 * 5 + 4] = 1.0f / (1.0f + __expf(-am1[0]));
      }
    }
  }
}

// 32x32x16 bf16 MFMA, A = weights (m=feature), B = activations (n=point).
// Activations ping-pong between register banks pin/pout (uint4[2][8], feature
// order matching phi'd MFMA-B exactly -> B = bit_cast(pin[m][s]), zero build).
// r13: DEEP WINDOW (DEPTH 16). r12 triple-confirmed the spill law (any cap
// < (256,2) spills catastrophically) -> 2 waves/SIMD is final, and at 2
// waves/SIMD the per-wave budget is 256 unified regs (m69) — r11 used only
// ~172. r11's lifetime data gives the latency model: position time =
// max(64 cyc MFMA-pipe, L_eff/DEPTH); measured 134 cyc @ DEPTH 8 =>
// L_eff ~= 1070 cyc (L2 under 1024-wave load >> unloaded ~200). DEPTH 16
// (64 VGPR, total ~204 < 256) -> position ~67 cyc -> per-wave duty ~45%,
// x2 waves -> pipe ~85-90%. Barrier-free all-L2 structure unchanged (r11).
// S: k-steps. SL: k-steps from pin (rest from tail). NT: 32-feature tiles.
// OUTM: 0=pack pout, 1=d2_3 (pack t<4 + density/blend), 2=c_1 (rgb only).
template <int S, int SL, int NT, bool RELU, int OUTM>
__device__ __forceinline__ void run_layer(const unsigned short* __restrict__ wsrc,
                                          const uint4 (&pin)[2][8],
                                          uint4 (&pout)[2][8],
                                          const bf16x8 (&tail)[2][4],
                                          float* __restrict__ out, int base, int tid) {
  const int lane = tid & 63;
  const int w = tid >> 6;
  const int q2 = lane >> 5;
  const int l31 = lane & 31;
  const int pt0 = base + w * 64 + l31;
  const int pt1 = pt0 + 32;

  const uint4* __restrict__ wp = (const uint4*)wsrc;

  constexpr int TOT = NT * S;
  constexpr int DEPTH = 16;  // 64 VGPR window ~= 1024 cyc of L2-latency cover
  bf16x8 win[DEPTH];

  // prologue: fill the window
#pragma unroll
  for (int p = 0; p < DEPTH && p < TOT; ++p)
    win[p] = __builtin_bit_cast(bf16x8, wp[p * 64 + lane]);

  floatx16 a0, a1;
#pragma unroll
  for (int p = 0; p < TOT; ++p) {
    const int t = p / S, s = p % S;
    if (s == 0) {
#pragma unroll
      for (int i = 0; i < 16; ++i) { a0[i] = 0.0f; a1[i] = 0.0f; }
    }
    bf16x8 A = win[p % DEPTH];                       // waits only this slot
    if (p + DEPTH < TOT)
      win[p % DEPTH] = __builtin_bit_cast(bf16x8, wp[(p + DEPTH) * 64 + lane]);
    bf16x8 B0 = (s < SL) ? __builtin_bit_cast(bf16x8, pin[0][(s < SL) ? s : 0])
                         : tail[0][s - SL];
    bf16x8 B1 = (s < SL) ? __builtin_bit_cast(bf16x8, pin[1][(s < SL) ? s : 0])
                         : tail[1][s - SL];
    a0 = __builtin_amdgcn_mfma_f32_32x32x16_bf16(A, B0, a0, 0, 0, 0);
    a1 = __builtin_amdgcn_mfma_f32_32x32x16_bf16(A, B1, a1, 0, 0, 0);
    if (s == S - 1)
      store_tile<RELU, OUTM>(t, a0, a1, pout, out, q2, pt0, pt1);
  }
}

// launch_bounds(256,2): the unique no-spill point — triple-confirmed (r2/r4/
// r12: any tighter cap spills 0.6-2.4 GB scratch/LDS). At 2 waves/SIMD the
// unified budget is 256/wave; natural live set ~204 with the deep window.
// Spill tripwire: WRITE_SIZE >> 25 MB => retreat DEPTH 16->12.
__global__ __launch_bounds__(256, 2) void nerf_main(const float* __restrict__ x,
                                                    const unsigned short* __restrict__ ws,
                                                    float* __restrict__ out) {
  const int tid = (int)threadIdx.x;
  const int base = (int)blockIdx.x * 256;
  const int lane = tid & 63;
  const int w = tid >> 6;
  const int q2 = lane >> 5;
  const int l31 = lane & 31;
  const int pt0 = base + w * 64 + l31;

  // per-lane x in registers (pt fixed per lane for whole kernel)
  float x0[6], x1[6];
  {
    const float* a = x + (size_t)pt0 * 6;
    const float* b = x + (size_t)(pt0 + 32) * 6;
#pragma unroll
    for (int c = 0; c < 3; ++c) {
      float2 u = *(const float2*)(a + 2 * c);
      float2 v = *(const float2*)(b + 2 * c);
      x0[2 * c] = u.x; x0[2 * c + 1] = u.y;
      x1[2 * c] = v.x; x1[2 * c + 1] = v.y;
    }
  }

  // positional trig frags computed ONCE (used by d1_0 and d2_0)
  bf16x8 pkt[2][4];
#pragma unroll
  for (int sl = 0; sl < 4; ++sl) {
    pkt[0][sl] = trig_frag<0>(x0, q2, sl);
    pkt[1][sl] = trig_frag<0>(x1, q2, sl);
  }

  // activation ping-pong register banks
  uint4 P0[2][8], P1[2][8];

  //          S   SL NT relu  out     wsrc
  run_layer< 4, 0, 4, true , 0>(ws + 0u,      P0, P0, pkt, out, base, tid); // d1_0 (in unused)
  run_layer< 8, 8, 4, true , 0>(ws + 8192u,   P0, P1, pkt, out, base, tid); // d1_1
  run_layer< 8, 8, 4, false, 0>(ws + 24576u,  P1, P0, pkt, out, base, tid); // d1_2 -> part1
  run_layer<12, 8, 4, true , 0>(ws + 40960u,  P0, P1, pkt, out, base, tid); // d2_0 [part1|enc_pos]
  run_layer< 8, 8, 4, true , 0>(ws + 65536u,  P1, P0, pkt, out, base, tid); // d2_1
  run_layer< 8, 8, 4, true , 0>(ws + 81920u,  P0, P1, pkt, out, base, tid); // d2_2
  run_layer< 8, 8, 5, false, 1>(ws + 98304u,  P1, P0, pkt, out, base, tid); // d2_3

  // view trig frags (pkt regs dead after d2_0 -> reuse pressure window)
  // only [*][0..1] are ever read (c_0: S-SL = 2 tail steps)
  bf16x8 vw[2][4];
#pragma unroll
  for (int sl = 0; sl < 2; ++sl) {
    vw[0][sl] = trig_frag<1>(x0, q2, sl);
    vw[1][sl] = trig_frag<1>(x1, q2, sl);
  }
  vw[0][2] = vw[0][0]; vw[0][3] = vw[0][0];
  vw[1][2] = vw[1][0]; vw[1][3] = vw[1][0];

  run_layer<10, 8, 4, true , 0>(ws + 118784u, P0, P1, vw,  out, base, tid); // c_0 [feature|enc_view]
  run_layer< 8, 8, 1, false, 2>(ws + 139264u, P1, P0, pkt, out, base, tid); // c_1 -> rgb
}

extern "C" void kernel_launch(void* const* d_in, const int* in_sizes, int n_in,
                              void* d_out, int out_size, void* d_ws, size_t ws_size,
                              hipStream_t stream) {
  (void)n_in; (void)out_size; (void)ws_size;
  const float* x = (const float*)d_in[0];
  SrcPtrs sp;
  for (int i = 0; i < 9; ++i) sp.p[i] = (const float*)d_in[1 + i];
  unsigned short* ws = (unsigned short*)d_ws;
  float* out = (float*)d_out;
  const int N = in_sizes[0] / 6;

  prep_zero<<<70, 256, 0, stream>>>(ws);
  prep_fill<<<144, 256, 0, stream>>>(sp, ws);
  nerf_main<<<N / 256, 256, 0, stream>>>(x, ws, out);
}